// Round 8
// baseline (174.027 us; speedup 1.0000x reference)
//
#include <hip/hip_runtime.h>

#define BLOCK 512   // 8 waves
#define GRID  768   // 3 blocks/CU x 256 CU; LDS 52224*3 = 156672 <= 163840

typedef __attribute__((ext_vector_type(8))) short short8;   // 8 x bf16
typedef __attribute__((ext_vector_type(4))) float f32x4;    // MFMA C/D frag

#define TWOLOG2E  2.8853900817779268f   // 2*log2(e), folded into g/beta
#define NLOG2E   -1.4426950408889634f   // -log2(e), folded into W4/b4

#define HP 66   // h-tile pitch in bf16: 33 dwords -> 33*cl mod 32 = cl (2-way, free)

__device__ __forceinline__ unsigned short f2bf(float f) {
    unsigned u = __builtin_bit_cast(unsigned, f);
    u += 0x7FFFu + ((u >> 16) & 1u);
    return (unsigned short)(u >> 16);
}

__device__ __forceinline__ unsigned pkbf(float lo, float hi) {
    // dst[15:0]=bf16(lo), dst[31:16]=bf16(hi), RNE
    unsigned r;
    asm("v_cvt_pk_bf16_f32 %0, %1, %2" : "=v"(r) : "v"(lo), "v"(hi));
    return r;
}

// tanh(v*g+bt) with pre-scaled z = v*g' + bt' (g' = 2log2e*g):
// tanh = 1 - 2*rcp(1 + exp2(z)); exact at +-inf
__device__ __forceinline__ float tanh_z(float z) {
    float e = __builtin_amdgcn_exp2f(z);
    return fmaf(-2.0f, __builtin_amdgcn_rcpf(1.0f + e), 1.0f);
}

// LayerNorm + tanh, transposed layout: lane holds edge `cl`, h-cols m*16+kg*4+i.
#define LN_T(PB, PG, PT, A)                                                   \
    {                                                                         \
        float s = 0.f, q = 0.f;                                               \
        _Pragma("unroll")                                                     \
        for (int m = 0; m < 4; ++m) {                                         \
            const float4 pb = *reinterpret_cast<const float4*>(               \
                plds + (PB) * 64 + m * 16 + kg4);                             \
            A[m][0] += pb.x; A[m][1] += pb.y;                                 \
            A[m][2] += pb.z; A[m][3] += pb.w;                                 \
            s += (A[m][0] + A[m][1]) + (A[m][2] + A[m][3]);                   \
            q = fmaf(A[m][0], A[m][0], q); q = fmaf(A[m][1], A[m][1], q);     \
            q = fmaf(A[m][2], A[m][2], q); q = fmaf(A[m][3], A[m][3], q);     \
        }                                                                     \
        s += __shfl_xor(s, 16); s += __shfl_xor(s, 32);                       \
        q += __shfl_xor(q, 16); q += __shfl_xor(q, 32);                       \
        const float mu = s * 0.015625f;                                       \
        float var = fmaf(q, 0.015625f, -mu * mu);                             \
        var = fmaxf(var, 0.0f);                                               \
        const float rs = __builtin_amdgcn_rsqf(var + 1e-5f);                  \
        const float mrs = mu * rs;                                            \
        _Pragma("unroll")                                                     \
        for (int m = 0; m < 4; ++m) {                                         \
            const float4 pg = *reinterpret_cast<const float4*>(               \
                plds + (PG) * 64 + m * 16 + kg4);                             \
            const float4 pt = *reinterpret_cast<const float4*>(               \
                plds + (PT) * 64 + m * 16 + kg4);                             \
            A[m][0] = tanh_z(fmaf(fmaf(A[m][0], rs, -mrs), pg.x, pt.x));      \
            A[m][1] = tanh_z(fmaf(fmaf(A[m][1], rs, -mrs), pg.y, pt.y));      \
            A[m][2] = tanh_z(fmaf(fmaf(A[m][2], rs, -mrs), pg.z, pt.z));      \
            A[m][3] = tanh_z(fmaf(fmaf(A[m][3], rs, -mrs), pg.w, pt.w));      \
        }                                                                     \
    }

#define H_STORE_T(A)                                                          \
    _Pragma("unroll")                                                         \
    for (int m = 0; m < 4; ++m) {                                             \
        uint2 u2;                                                             \
        u2.x = pkbf(A[m][0], A[m][1]);                                        \
        u2.y = pkbf(A[m][2], A[m][3]);                                        \
        *reinterpret_cast<uint2*>(hwv + cl * HP + m * 16 + kg4) = u2;         \
    }

// issue the 8 x-gather loads (f32 path) or 4 bf16 loads for a tile
#define GATHER(NS, NE)                                                        \
    _Pragma("unroll")                                                         \
    for (int kb = 0; kb < 4; ++kb) {                                          \
        const unsigned off = (unsigned)(kb < 2 ? (NS) : (NE)) * 64u           \
                           + (unsigned)((kb & 1) * 32 + kg * 8);              \
        if constexpr (PREBF) {                                                \
            xa[kb] = *reinterpret_cast<const short8*>(xb + off);              \
        } else {                                                              \
            u[2 * kb]     = *reinterpret_cast<const float4*>(xf + off);       \
            u[2 * kb + 1] = *reinterpret_cast<const float4*>(xf + off + 4);   \
        }                                                                     \
    }

#define LDIDX(T, A_, B_)                                                      \
    {                                                                         \
        const int tc_ = min((T), ntiles - 1);                                 \
        const int er_ = min((tc_ << 4) + cl, E - 1);                          \
        A_ = ei[er_]; B_ = ei[E + er_];                                       \
    }

template<bool PREBF>
__global__ __launch_bounds__(BLOCK) void edge_mlp_t(
    const void* __restrict__ xsrc, const int* __restrict__ ei,
    const float* __restrict__ W1, const float* __restrict__ b1,
    const float* __restrict__ g1, const float* __restrict__ bt1,
    const float* __restrict__ W2, const float* __restrict__ b2,
    const float* __restrict__ g2, const float* __restrict__ bt2,
    const float* __restrict__ W3, const float* __restrict__ b3,
    const float* __restrict__ g3, const float* __restrict__ bt3,
    const float* __restrict__ W4, const float* __restrict__ b4,
    float* __restrict__ out, int E)
{
    __shared__ unsigned short wlds[32 * 512];          // 32 KiB W^T frags
    __shared__ unsigned short hlds[8 * 16 * HP];       // per-wave [16 edge][HP] bf16
    __shared__ float plds[10 * 64];                    // b,g',bt' x3 + W4'

    const int tid  = threadIdx.x;
    const int widx = tid >> 6;
    const int lane = tid & 63;
    const int kg   = lane >> 4;   // 0..3
    const int cl   = lane & 15;   // 0..15 = edge within tile
    const int kg4  = kg * 4;

    for (int fi = widx; fi < 32; fi += 8) {
        const float* Wsrc; int m, kb;
        if (fi < 16) { Wsrc = W1; m = fi >> 2; kb = fi & 3; }
        else { int f = fi - 16; Wsrc = (f < 8) ? W2 : W3; f &= 7; m = f >> 1; kb = f & 1; }
        const float* src = Wsrc + (kb * 32 + kg * 8) * 64 + m * 16 + cl;
        short8 pk8;
        #pragma unroll
        for (int j = 0; j < 8; ++j) pk8[j] = (short)f2bf(src[j * 64]);
        *reinterpret_cast<short8*>(&wlds[fi * 512 + lane * 8]) = pk8;
    }
    // params -> LDS with constant folding: g,bt scaled by 2log2e; W4 by -log2e
    for (int i = tid; i < 640; i += BLOCK) {
        const int p = i >> 6, c = i & 63;
        const float* sp; float sc;
        switch (p) {
            case 0: sp = b1;  sc = 1.0f;     break;
            case 1: sp = g1;  sc = TWOLOG2E; break;
            case 2: sp = bt1; sc = TWOLOG2E; break;
            case 3: sp = b2;  sc = 1.0f;     break;
            case 4: sp = g2;  sc = TWOLOG2E; break;
            case 5: sp = bt2; sc = TWOLOG2E; break;
            case 6: sp = b3;  sc = 1.0f;     break;
            case 7: sp = g3;  sc = TWOLOG2E; break;
            case 8: sp = bt3; sc = TWOLOG2E; break;
            default: sp = W4; sc = NLOG2E;   break;
        }
        plds[i] = sp[c] * sc;
    }
    const float b4s = b4[0] * NLOG2E;
    __syncthreads();

    const unsigned short* xb = (const unsigned short*)xsrc;
    const float*          xf = (const float*)xsrc;
    unsigned short* hwv = hlds + widx * (16 * HP);

    const int ntiles = (E + 15) >> 4;
    const int NW = (int)gridDim.x * 8;

    int t = (int)blockIdx.x * 8 + widx;

    // ---- 2-deep pipeline state: x data of tile t, indices of tile t+NW ----
    float4 u[8];
    short8 xa[4];
    int ns1, ne1;
    {
        int ns0, ne0;
        LDIDX(t, ns0, ne0);
        GATHER(ns0, ne0);
        LDIDX(t + NW, ns1, ne1);
    }

    for (; t < ntiles; t += NW) {
        // ---- consume this tile's x (in flight since last iteration) ----
        short8 af[4];
        if constexpr (PREBF) {
            #pragma unroll
            for (int kb = 0; kb < 4; ++kb) af[kb] = xa[kb];
        } else {
            #pragma unroll
            for (int kb = 0; kb < 4; ++kb) {
                uint4 tp_;
                tp_.x = pkbf(u[2 * kb].x,     u[2 * kb].y);
                tp_.y = pkbf(u[2 * kb].z,     u[2 * kb].w);
                tp_.z = pkbf(u[2 * kb + 1].x, u[2 * kb + 1].y);
                tp_.w = pkbf(u[2 * kb + 1].z, u[2 * kb + 1].w);
                af[kb] = __builtin_bit_cast(short8, tp_);
            }
        }

        // ---- immediately re-issue: next tile's x + next-next indices ----
        GATHER(ns1, ne1);
        LDIDX(t + 2 * NW, ns1, ne1);

        // ---------- Layer 1 ----------
        f32x4 acc[4] = {{0,0,0,0},{0,0,0,0},{0,0,0,0},{0,0,0,0}};
        #pragma unroll
        for (int kb = 0; kb < 4; ++kb) {
            #pragma unroll
            for (int m = 0; m < 4; ++m) {
                const short8 wf = *reinterpret_cast<const short8*>(
                    &wlds[(m * 4 + kb) * 512 + lane * 8]);
                acc[m] = __builtin_amdgcn_mfma_f32_16x16x32_bf16(wf, af[kb], acc[m], 0, 0, 0);
            }
        }
        LN_T(0, 1, 2, acc);
        H_STORE_T(acc);

        // ---------- Layer 2 ----------
        f32x4 acc2[4] = {{0,0,0,0},{0,0,0,0},{0,0,0,0},{0,0,0,0}};
        #pragma unroll
        for (int kb = 0; kb < 2; ++kb) {
            const short8 hf = *reinterpret_cast<const short8*>(
                hwv + cl * HP + kb * 32 + kg * 8);
            #pragma unroll
            for (int m = 0; m < 4; ++m) {
                const short8 wf = *reinterpret_cast<const short8*>(
                    &wlds[(16 + m * 2 + kb) * 512 + lane * 8]);
                acc2[m] = __builtin_amdgcn_mfma_f32_16x16x32_bf16(wf, hf, acc2[m], 0, 0, 0);
            }
        }
        LN_T(3, 4, 5, acc2);
        H_STORE_T(acc2);

        // ---------- Layer 3 ----------
        f32x4 acc3[4] = {{0,0,0,0},{0,0,0,0},{0,0,0,0},{0,0,0,0}};
        #pragma unroll
        for (int kb = 0; kb < 2; ++kb) {
            const short8 hf = *reinterpret_cast<const short8*>(
                hwv + cl * HP + kb * 32 + kg * 8);
            #pragma unroll
            for (int m = 0; m < 4; ++m) {
                const short8 wf = *reinterpret_cast<const short8*>(
                    &wlds[(24 + m * 2 + kb) * 512 + lane * 8]);
                acc3[m] = __builtin_amdgcn_mfma_f32_16x16x32_bf16(wf, hf, acc3[m], 0, 0, 0);
            }
        }
        LN_T(6, 7, 8, acc3);

        // ---------- Layer 4: in-lane dot (W4 pre-scaled) + sigmoid ----------
        float p = 0.f;
        #pragma unroll
        for (int m = 0; m < 4; ++m) {
            const float4 w4 = *reinterpret_cast<const float4*>(
                plds + 9 * 64 + m * 16 + kg4);
            p = fmaf(acc3[m][0], w4.x, p); p = fmaf(acc3[m][1], w4.y, p);
            p = fmaf(acc3[m][2], w4.z, p); p = fmaf(acc3[m][3], w4.w, p);
        }
        p += __shfl_xor(p, 16); p += __shfl_xor(p, 32);
        if (kg == 0) {
            const int e = (t << 4) + cl;
            if (e < E) {
                // p already = -log2(e) * (h.W4 + b4)
                out[e] = __builtin_amdgcn_rcpf(
                    1.0f + __builtin_amdgcn_exp2f(p + b4s));
            }
        }
    }
}

__global__ __launch_bounds__(256) void cvt_x_bf16(const float* __restrict__ x,
                                                  unsigned short* __restrict__ xbf,
                                                  int n) {
    const int i = (blockIdx.x * 256 + threadIdx.x) * 8;
    if (i >= n) return;
    const float4 u0 = *reinterpret_cast<const float4*>(x + i);
    const float4 u1 = *reinterpret_cast<const float4*>(x + i + 4);
    uint4 t;
    t.x = pkbf(u0.x, u0.y); t.y = pkbf(u0.z, u0.w);
    t.z = pkbf(u1.x, u1.y); t.w = pkbf(u1.z, u1.w);
    *reinterpret_cast<uint4*>(xbf + i) = t;
}

extern "C" void kernel_launch(void* const* d_in, const int* in_sizes, int n_in,
                              void* d_out, int out_size, void* d_ws, size_t ws_size,
                              hipStream_t stream) {
    const float* x   = (const float*)d_in[0];
    const int*   ei  = (const int*)  d_in[1];
    const float* W1  = (const float*)d_in[2];
    const float* b1  = (const float*)d_in[3];
    const float* g1  = (const float*)d_in[4];
    const float* bt1 = (const float*)d_in[5];
    const float* W2  = (const float*)d_in[6];
    const float* b2  = (const float*)d_in[7];
    const float* g2  = (const float*)d_in[8];
    const float* bt2 = (const float*)d_in[9];
    const float* W3  = (const float*)d_in[10];
    const float* b3  = (const float*)d_in[11];
    const float* g3  = (const float*)d_in[12];
    const float* bt3 = (const float*)d_in[13];
    const float* W4  = (const float*)d_in[14];
    const float* b4  = (const float*)d_in[15];
    float* out = (float*)d_out;

    const int E  = in_sizes[1] / 2;
    const int nX = in_sizes[0];                 // n_nodes * 64

    const bool prebf = (ws_size >= (size_t)nX * 2);

    if (prebf) {
        unsigned short* xbf = (unsigned short*)d_ws;
        const int grid_c = (nX / 8 + 255) / 256;
        hipLaunchKernelGGL(cvt_x_bf16, dim3(grid_c), dim3(256), 0, stream, x, xbf, nX);
        hipLaunchKernelGGL((edge_mlp_t<true>), dim3(GRID), dim3(BLOCK), 0, stream,
                           (const void*)xbf, ei, W1, b1, g1, bt1, W2, b2, g2, bt2,
                           W3, b3, g3, bt3, W4, b4, out, E);
    } else {
        hipLaunchKernelGGL((edge_mlp_t<false>), dim3(GRID), dim3(BLOCK), 0, stream,
                           (const void*)x, ei, W1, b1, g1, bt1, W2, b2, g2, bt2,
                           W3, b3, g3, bt3, W4, b4, out, E);
    }
}

// Round 9
// 164.110 us; speedup vs baseline: 1.0604x; 1.0604x over previous
//
#include <hip/hip_runtime.h>

#define BLOCK 512   // 8 waves
#define GRID  512   // 2 blocks/CU co-resident (VGPR 128-tier); multiple of resident set

typedef __attribute__((ext_vector_type(8)))  short short8;   // 8 x bf16
typedef __attribute__((ext_vector_type(16))) float f32x16;   // 32x32 MFMA C/D

#define TWOLOG2E  2.8853900817779268f   // 2*log2(e), folded into g/beta
#define NLOG2E   -1.4426950408889634f   // -log2(e), folded into W4/b4
#define HP 66   // h-tile pitch in bf16 (33 dwords): measured 0 bank conflicts

__device__ __forceinline__ unsigned short f2bf(float f) {
    unsigned u = __builtin_bit_cast(unsigned, f);
    u += 0x7FFFu + ((u >> 16) & 1u);
    return (unsigned short)(u >> 16);
}

__device__ __forceinline__ unsigned pkbf(float lo, float h_) {
    unsigned r;
    asm("v_cvt_pk_bf16_f32 %0, %1, %2" : "=v"(r) : "v"(lo), "v"(h_));
    return r;
}

// tanh via pre-scaled z = v*g' + bt' (g' = 2log2e*g): 1 - 2*rcp(1+exp2(z))
__device__ __forceinline__ float tanh_z(float z) {
    float e = __builtin_amdgcn_exp2f(z);
    return fmaf(-2.0f, __builtin_amdgcn_rcpf(1.0f + e), 1.0f);
}

// ---- LayerNorm+tanh, 32x32 transposed layout ----
// lane (el=lane&31, hi=lane>>5) holds edge el, feats mf*32 + qq*8 + 4*hi + i
#define LN32(PB, PG, PT, A)                                                   \
    {                                                                         \
        float s = 0.f, q = 0.f;                                               \
        _Pragma("unroll")                                                     \
        for (int mf = 0; mf < 2; ++mf) {                                      \
            _Pragma("unroll")                                                 \
            for (int qq = 0; qq < 4; ++qq) {                                  \
                const float4 pb = *reinterpret_cast<const float4*>(           \
                    plds + (PB) * 64 + mf * 32 + qq * 8 + hi4);               \
                float r0 = A[mf][qq*4+0] + pb.x;                              \
                float r1 = A[mf][qq*4+1] + pb.y;                              \
                float r2 = A[mf][qq*4+2] + pb.z;                              \
                float r3 = A[mf][qq*4+3] + pb.w;                              \
                A[mf][qq*4+0] = r0; A[mf][qq*4+1] = r1;                       \
                A[mf][qq*4+2] = r2; A[mf][qq*4+3] = r3;                       \
                s += (r0 + r1) + (r2 + r3);                                   \
                q = fmaf(r0, r0, q); q = fmaf(r1, r1, q);                     \
                q = fmaf(r2, r2, q); q = fmaf(r3, r3, q);                     \
            }                                                                 \
        }                                                                     \
        s += __shfl_xor(s, 32); q += __shfl_xor(q, 32);                       \
        const float mu = s * 0.015625f;                                       \
        float var = fmaf(q, 0.015625f, -mu * mu);                             \
        var = fmaxf(var, 0.0f);                                               \
        const float rs = __builtin_amdgcn_rsqf(var + 1e-5f);                  \
        const float mrs = mu * rs;                                            \
        _Pragma("unroll")                                                     \
        for (int mf = 0; mf < 2; ++mf) {                                      \
            _Pragma("unroll")                                                 \
            for (int qq = 0; qq < 4; ++qq) {                                  \
                const float4 pg = *reinterpret_cast<const float4*>(           \
                    plds + (PG) * 64 + mf * 32 + qq * 8 + hi4);               \
                const float4 pt = *reinterpret_cast<const float4*>(           \
                    plds + (PT) * 64 + mf * 32 + qq * 8 + hi4);               \
                A[mf][qq*4+0] = tanh_z(fmaf(fmaf(A[mf][qq*4+0], rs, -mrs), pg.x, pt.x)); \
                A[mf][qq*4+1] = tanh_z(fmaf(fmaf(A[mf][qq*4+1], rs, -mrs), pg.y, pt.y)); \
                A[mf][qq*4+2] = tanh_z(fmaf(fmaf(A[mf][qq*4+2], rs, -mrs), pg.z, pt.z)); \
                A[mf][qq*4+3] = tanh_z(fmaf(fmaf(A[mf][qq*4+3], rs, -mrs), pg.w, pt.w)); \
            }                                                                 \
        }                                                                     \
    }

// scatter 32 bf16 (8 quads) to this wave's h tile: 8x ds_write_b64, 2-way banks
#define H_STORE32(A)                                                          \
    _Pragma("unroll")                                                         \
    for (int mf = 0; mf < 2; ++mf) {                                          \
        _Pragma("unroll")                                                     \
        for (int qq = 0; qq < 4; ++qq) {                                      \
            uint2 u2;                                                         \
            u2.x = pkbf(A[mf][qq*4+0], A[mf][qq*4+1]);                        \
            u2.y = pkbf(A[mf][qq*4+2], A[mf][qq*4+3]);                        \
            *reinterpret_cast<uint2*>(hwv + el * HP + mf * 32 + qq * 8 + hi4) = u2; \
        }                                                                     \
    }

// x-gather for a 32-edge tile: lane (el,hi) loads feats 16*(ks&3)+8*hi+[0..8)
// of src node (ks<4) / dst node (ks>=4) of edge el.  8 x 16B loads.
#define GATHER_BF(NS, NE)                                                     \
    _Pragma("unroll")                                                         \
    for (int ks = 0; ks < 8; ++ks) {                                          \
        const unsigned off = (unsigned)(ks < 4 ? (NS) : (NE)) * 64u           \
                           + (unsigned)(16 * (ks & 3) + 8 * hi);              \
        xa[ks] = *reinterpret_cast<const short8*>(xb + off);                  \
    }

#define LDIDX(T, A_, B_)                                                      \
    {                                                                         \
        const int tc_ = min((T), ntiles - 1);                                 \
        const int er_ = min((tc_ << 5) + el, E - 1);                          \
        A_ = ei[er_]; B_ = ei[E + er_];                                       \
    }

template<bool PREBF>
__global__ __launch_bounds__(BLOCK) void edge_mlp_t(
    const void* __restrict__ xsrc, const int* __restrict__ ei,
    const float* __restrict__ W1, const float* __restrict__ b1,
    const float* __restrict__ g1, const float* __restrict__ bt1,
    const float* __restrict__ W2, const float* __restrict__ b2,
    const float* __restrict__ g2, const float* __restrict__ bt2,
    const float* __restrict__ W3, const float* __restrict__ b3,
    const float* __restrict__ g3, const float* __restrict__ bt3,
    const float* __restrict__ W4, const float* __restrict__ b4,
    float* __restrict__ out, int E)
{
    // W^T frags for 32x32x16: frag(fi): lane holds W[ks*16 + hi*8 + j][mf*32 + el]
    // L1: fi = mf*8+ks (16 frags); L2: 16 + mf*4+ks; L3: 24 + mf*4+ks
    __shared__ unsigned short wlds[32 * 512];          // 32 KiB
    __shared__ unsigned short hlds[8 * 32 * HP];       // per-wave [32 edge][HP] bf16
    __shared__ float plds[10 * 64];                    // b,g',bt' x3 + W4'

    const int tid  = threadIdx.x;
    const int widx = tid >> 6;
    const int lane = tid & 63;
    const int el   = lane & 31;   // edge within tile
    const int hi   = lane >> 5;   // k-half / feature-quad selector
    const int hi4  = hi * 4;

    for (int fi = widx; fi < 32; fi += 8) {
        const float* Wsrc; int mf, ks;
        if (fi < 16) { Wsrc = W1; mf = fi >> 3; ks = fi & 7; }
        else { int f = fi - 16; Wsrc = (f < 8) ? W2 : W3; f &= 7; mf = f >> 2; ks = f & 3; }
        const float* src = Wsrc + (ks * 16 + hi * 8) * 64 + mf * 32 + el;
        short8 pk8;
        #pragma unroll
        for (int j = 0; j < 8; ++j) pk8[j] = (short)f2bf(src[j * 64]);
        *reinterpret_cast<short8*>(&wlds[fi * 512 + lane * 8]) = pk8;
    }
    // params -> LDS; g,bt scaled by 2log2e, W4 by -log2e
    for (int i = tid; i < 640; i += BLOCK) {
        const int p = i >> 6, c = i & 63;
        const float* sp; float sc;
        switch (p) {
            case 0: sp = b1;  sc = 1.0f;     break;
            case 1: sp = g1;  sc = TWOLOG2E; break;
            case 2: sp = bt1; sc = TWOLOG2E; break;
            case 3: sp = b2;  sc = 1.0f;     break;
            case 4: sp = g2;  sc = TWOLOG2E; break;
            case 5: sp = bt2; sc = TWOLOG2E; break;
            case 6: sp = b3;  sc = 1.0f;     break;
            case 7: sp = g3;  sc = TWOLOG2E; break;
            case 8: sp = bt3; sc = TWOLOG2E; break;
            default: sp = W4; sc = NLOG2E;   break;
        }
        plds[i] = sp[c] * sc;
    }
    const float b4s = b4[0] * NLOG2E;
    __syncthreads();

    const unsigned short* xb = (const unsigned short*)xsrc;
    const float*          xf = (const float*)xsrc;
    unsigned short* hwv = hlds + widx * (32 * HP);

    const int ntiles = (E + 31) >> 5;
    const int NW = (int)gridDim.x * 8;

    int t = (int)blockIdx.x * 8 + widx;
    int ns0, ne0, ns1, ne1;
    short8 xa[8];
    LDIDX(t, ns0, ne0);
    if constexpr (PREBF) { GATHER_BF(ns0, ne0); }   // tile t data in flight
    LDIDX(t + NW, ns1, ne1);

    for (; t < ntiles; t += NW) {
        if constexpr (!PREBF) {
            // fallback: gather f32 + convert (not pipelined)
            #pragma unroll
            for (int ks = 0; ks < 8; ++ks) {
                const unsigned off = (unsigned)(ks < 4 ? ns0 : ne0) * 64u
                                   + (unsigned)(16 * (ks & 3) + 8 * hi);
                const float4 u0 = *reinterpret_cast<const float4*>(xf + off);
                const float4 u1 = *reinterpret_cast<const float4*>(xf + off + 4);
                uint4 tp_;
                tp_.x = pkbf(u0.x, u0.y); tp_.y = pkbf(u0.z, u0.w);
                tp_.z = pkbf(u1.x, u1.y); tp_.w = pkbf(u1.z, u1.w);
                xa[ks] = __builtin_bit_cast(short8, tp_);
            }
        }

        // ---------- Layer 1: C^T[64f][32e] = W1^T (2 mf-frags) x X[128][32] ----------
        f32x16 acc[2] = {{0,0,0,0,0,0,0,0,0,0,0,0,0,0,0,0},
                         {0,0,0,0,0,0,0,0,0,0,0,0,0,0,0,0}};
        #pragma unroll
        for (int ks = 0; ks < 8; ++ks) {
            #pragma unroll
            for (int mf = 0; mf < 2; ++mf) {
                const short8 wf = *reinterpret_cast<const short8*>(
                    &wlds[(mf * 8 + ks) * 512 + lane * 8]);
                acc[mf] = __builtin_amdgcn_mfma_f32_32x32x16_bf16(wf, xa[ks], acc[mf], 0, 0, 0);
            }
        }

        // xa consumed -> issue next tile's gather now; L2-L4 (~1500cy) hides it
        if constexpr (PREBF) { GATHER_BF(ns1, ne1); }
        else { ns0 = ns1; ne0 = ne1; }
        LDIDX(t + 2 * NW, ns1, ne1);

        LN32(0, 1, 2, acc);
        H_STORE32(acc);

        // ---------- Layer 2 ----------
        f32x16 acc2[2] = {{0,0,0,0,0,0,0,0,0,0,0,0,0,0,0,0},
                          {0,0,0,0,0,0,0,0,0,0,0,0,0,0,0,0}};
        #pragma unroll
        for (int ks = 0; ks < 4; ++ks) {
            const short8 hf = *reinterpret_cast<const short8*>(
                hwv + el * HP + ks * 16 + hi * 8);
            #pragma unroll
            for (int mf = 0; mf < 2; ++mf) {
                const short8 wf = *reinterpret_cast<const short8*>(
                    &wlds[(16 + mf * 4 + ks) * 512 + lane * 8]);
                acc2[mf] = __builtin_amdgcn_mfma_f32_32x32x16_bf16(wf, hf, acc2[mf], 0, 0, 0);
            }
        }
        LN32(3, 4, 5, acc2);
        H_STORE32(acc2);

        // ---------- Layer 3 ----------
        f32x16 acc3[2] = {{0,0,0,0,0,0,0,0,0,0,0,0,0,0,0,0},
                          {0,0,0,0,0,0,0,0,0,0,0,0,0,0,0,0}};
        #pragma unroll
        for (int ks = 0; ks < 4; ++ks) {
            const short8 hf = *reinterpret_cast<const short8*>(
                hwv + el * HP + ks * 16 + hi * 8);
            #pragma unroll
            for (int mf = 0; mf < 2; ++mf) {
                const short8 wf = *reinterpret_cast<const short8*>(
                    &wlds[(24 + mf * 4 + ks) * 512 + lane * 8]);
                acc3[mf] = __builtin_amdgcn_mfma_f32_32x32x16_bf16(wf, hf, acc3[mf], 0, 0, 0);
            }
        }
        LN32(6, 7, 8, acc3);

        // ---------- Layer 4: in-lane dot (W4 pre-scaled) + sigmoid ----------
        float p = 0.f;
        #pragma unroll
        for (int mf = 0; mf < 2; ++mf) {
            #pragma unroll
            for (int qq = 0; qq < 4; ++qq) {
                const float4 w4 = *reinterpret_cast<const float4*>(
                    plds + 9 * 64 + mf * 32 + qq * 8 + hi4);
                p = fmaf(acc3[mf][qq*4+0], w4.x, p);
                p = fmaf(acc3[mf][qq*4+1], w4.y, p);
                p = fmaf(acc3[mf][qq*4+2], w4.z, p);
                p = fmaf(acc3[mf][qq*4+3], w4.w, p);
            }
        }
        p += __shfl_xor(p, 32);
        if (lane < 32) {
            const int e = (t << 5) + lane;
            if (e < E) {
                out[e] = __builtin_amdgcn_rcpf(
                    1.0f + __builtin_amdgcn_exp2f(p + b4s));
            }
        }
    }
}

__global__ __launch_bounds__(256) void cvt_x_bf16(const float* __restrict__ x,
                                                  unsigned short* __restrict__ xbf,
                                                  int n) {
    const int i = (blockIdx.x * 256 + threadIdx.x) * 8;
    if (i >= n) return;
    const float4 u0 = *reinterpret_cast<const float4*>(x + i);
    const float4 u1 = *reinterpret_cast<const float4*>(x + i + 4);
    uint4 t;
    t.x = pkbf(u0.x, u0.y); t.y = pkbf(u0.z, u0.w);
    t.z = pkbf(u1.x, u1.y); t.w = pkbf(u1.z, u1.w);
    *reinterpret_cast<uint4*>(xbf + i) = t;
}

extern "C" void kernel_launch(void* const* d_in, const int* in_sizes, int n_in,
                              void* d_out, int out_size, void* d_ws, size_t ws_size,
                              hipStream_t stream) {
    const float* x   = (const float*)d_in[0];
    const int*   ei  = (const int*)  d_in[1];
    const float* W1  = (const float*)d_in[2];
    const float* b1  = (const float*)d_in[3];
    const float* g1  = (const float*)d_in[4];
    const float* bt1 = (const float*)d_in[5];
    const float* W2  = (const float*)d_in[6];
    const float* b2  = (const float*)d_in[7];
    const float* g2  = (const float*)d_in[8];
    const float* bt2 = (const float*)d_in[9];
    const float* W3  = (const float*)d_in[10];
    const float* b3  = (const float*)d_in[11];
    const float* g3  = (const float*)d_in[12];
    const float* bt3 = (const float*)d_in[13];
    const float* W4  = (const float*)d_in[14];
    const float* b4  = (const float*)d_in[15];
    float* out = (float*)d_out;

    const int E  = in_sizes[1] / 2;
    const int nX = in_sizes[0];                 // n_nodes * 64

    const bool prebf = (ws_size >= (size_t)nX * 2);

    if (prebf) {
        unsigned short* xbf = (unsigned short*)d_ws;
        const int grid_c = (nX / 8 + 255) / 256;
        hipLaunchKernelGGL(cvt_x_bf16, dim3(grid_c), dim3(256), 0, stream, x, xbf, nX);
        hipLaunchKernelGGL((edge_mlp_t<true>), dim3(GRID), dim3(BLOCK), 0, stream,
                           (const void*)xbf, ei, W1, b1, g1, bt1, W2, b2, g2, bt2,
                           W3, b3, g3, bt3, W4, b4, out, E);
    } else {
        hipLaunchKernelGGL((edge_mlp_t<false>), dim3(GRID), dim3(BLOCK), 0, stream,
                           (const void*)x, ei, W1, b1, g1, bt1, W2, b2, g2, bt2,
                           W3, b3, g3, bt3, W4, b4, out, E);
    }
}